// Round 1
// baseline (2797.250 us; speedup 1.0000x reference)
//
#include <hip/hip_runtime.h>

#define NGRAPH 2048

// ---------------- edge scatter: agg[dst] += X[src], 7 features ----------------
__global__ __launch_bounds__(256) void scatter7(
    const float* __restrict__ X, const int* __restrict__ src, const int* __restrict__ dst,
    float* __restrict__ agg, int E)
{
  long t = (long)blockIdx.x * 256 + threadIdx.x;
  int e = (int)(t >> 3);
  int j = (int)(t & 7);
  if (e >= E || j >= 7) return;
  int s = src[e], d = dst[e];
  atomicAdd(&agg[(long)d * 7 + j], X[(long)s * 7 + j]);
}

// ---------------- edge scatter: agg[dst] += H[src], 128 features ----------------
__global__ __launch_bounds__(256) void scatter128(
    const float* __restrict__ H, const int* __restrict__ src, const int* __restrict__ dst,
    float* __restrict__ agg, int E)
{
  long t = (long)blockIdx.x * 256 + threadIdx.x;
  int e = (int)(t >> 5);
  if (e >= E) return;
  int c = (int)(t & 31) * 4;
  int s = src[e], d = dst[e];
  const float4 v = *(const float4*)&H[(long)s * 128 + c];
  float* a = &agg[(long)d * 128 + c];
  atomicAdd(a + 0, v.x);
  atomicAdd(a + 1, v.y);
  atomicAdd(a + 2, v.z);
  atomicAdd(a + 3, v.w);
}

// ---------------- layer-1 first MLP: Y = relu((X+agg) @ W(7x128) + B) ----------------
__global__ __launch_bounds__(256) void gemm_in7(
    const float* __restrict__ X, const float* __restrict__ agg,
    const float* __restrict__ W, const float* __restrict__ B,
    float* __restrict__ Y, int Nn)
{
  __shared__ float zl[8][8];
  int tid = threadIdx.x;
  int blk = blockIdx.x;
  if (tid < 56) {
    int rr = tid / 7, k = tid - rr * 7;
    int row = blk * 8 + rr;
    zl[rr][k] = (row < Nn) ? (X[(long)row * 7 + k] + agg[(long)row * 7 + k]) : 0.f;
  }
  __syncthreads();
  int rr = tid >> 5;
  int c0 = (tid & 31) * 4;
  int row = blk * 8 + rr;
  float4 acc = *(const float4*)&B[c0];
#pragma unroll
  for (int k = 0; k < 7; ++k) {
    float z = zl[rr][k];
    float4 w = *(const float4*)&W[k * 128 + c0];
    acc.x += z * w.x; acc.y += z * w.y; acc.z += z * w.z; acc.w += z * w.w;
  }
  acc.x = fmaxf(acc.x, 0.f); acc.y = fmaxf(acc.y, 0.f);
  acc.z = fmaxf(acc.z, 0.f); acc.w = fmaxf(acc.w, 0.f);
  if (row < Nn) *(float4*)&Y[(long)row * 128 + c0] = acc;
}

// ---------------- generic K=128, Ncols=128 GEMM: Out = act(Z(+Zadd) @ W + B) ----------------
// block = 256 threads, tile = 64 rows x 128 cols, W staged in LDS (64 KB -> 2 blocks/CU)
template <bool RELU, bool ADDIN>
__global__ __launch_bounds__(256) void gemm_k128(
    const float* __restrict__ Z, const float* __restrict__ Zadd,
    const float* __restrict__ W, const float* __restrict__ B,
    float* __restrict__ Out, int M)
{
  __shared__ float wl[128 * 128];
  int tid = threadIdx.x;
  {
    const float4* Ws = (const float4*)W;
    float4* Wd = (float4*)wl;
#pragma unroll
    for (int i = 0; i < 16; ++i) Wd[i * 256 + tid] = Ws[i * 256 + tid];
  }
  __syncthreads();

  int rg = tid >> 5;
  int c0 = (tid & 31) * 4;
  int rbase = blockIdx.x * 64 + rg * 8;

  int rcl[8];
#pragma unroll
  for (int i = 0; i < 8; ++i) {
    int r = rbase + i;
    rcl[i] = (r < M) ? r : (M - 1);   // clamp loads; stores guarded below
  }

  float acc[8][4];
#pragma unroll
  for (int i = 0; i < 8; ++i)
#pragma unroll
    for (int j = 0; j < 4; ++j) acc[i][j] = 0.f;

#pragma unroll 2
  for (int kc = 0; kc < 128; kc += 4) {
    float zv[8][4];
#pragma unroll
    for (int i = 0; i < 8; ++i) {
      float4 z = *(const float4*)&Z[(long)rcl[i] * 128 + kc];
      if (ADDIN) {
        float4 a = *(const float4*)&Zadd[(long)rcl[i] * 128 + kc];
        z.x += a.x; z.y += a.y; z.z += a.z; z.w += a.w;
      }
      zv[i][0] = z.x; zv[i][1] = z.y; zv[i][2] = z.z; zv[i][3] = z.w;
    }
#pragma unroll
    for (int kk = 0; kk < 4; ++kk) {
      float4 w = *(const float4*)&wl[(kc + kk) * 128 + c0];
#pragma unroll
      for (int i = 0; i < 8; ++i) {
        float z = zv[i][kk];
        acc[i][0] += z * w.x; acc[i][1] += z * w.y;
        acc[i][2] += z * w.z; acc[i][3] += z * w.w;
      }
    }
  }

  float4 b = *(const float4*)&B[c0];
#pragma unroll
  for (int i = 0; i < 8; ++i) {
    int r = rbase + i;
    if (r < M) {
      float4 o;
      o.x = acc[i][0] + b.x; o.y = acc[i][1] + b.y;
      o.z = acc[i][2] + b.z; o.w = acc[i][3] + b.w;
      if (RELU) {
        o.x = fmaxf(o.x, 0.f); o.y = fmaxf(o.y, 0.f);
        o.z = fmaxf(o.z, 0.f); o.w = fmaxf(o.w, 0.f);
      }
      *(float4*)&Out[(long)r * 128 + c0] = o;
    }
  }
}

// ---------------- pooling: P[batch[i], colOff + :] += H[i, :]; run-length compressed ----------------
template <bool DO_CNT>
__global__ __launch_bounds__(256) void pool128(
    const float* __restrict__ H, const int* __restrict__ batch,
    float* __restrict__ P, float* __restrict__ cnt, int Nn, int colOff)
{
  long t = (long)blockIdx.x * 256 + threadIdx.x;
  int cg = (int)(t & 31);
  int chunk = (int)(t >> 5);
  int i0 = chunk * 16;
  if (i0 >= Nn) return;
  int c = cg * 4;
  float4 acc = {0.f, 0.f, 0.f, 0.f};
  int curb = -1;
  float runc = 0.f;
  for (int ii = 0; ii < 16; ++ii) {
    int i = i0 + ii;
    if (i >= Nn) break;
    int b = batch[i];
    if (b != curb) {
      if (curb >= 0) {
        float* p = &P[(long)curb * 384 + colOff + c];
        atomicAdd(p + 0, acc.x); atomicAdd(p + 1, acc.y);
        atomicAdd(p + 2, acc.z); atomicAdd(p + 3, acc.w);
        if (DO_CNT && cg == 0) atomicAdd(&cnt[curb], runc);
      }
      acc.x = acc.y = acc.z = acc.w = 0.f;
      runc = 0.f;
      curb = b;
    }
    const float4 v = *(const float4*)&H[(long)i * 128 + c];
    acc.x += v.x; acc.y += v.y; acc.z += v.z; acc.w += v.w;
    runc += 1.f;
  }
  if (curb >= 0) {
    float* p = &P[(long)curb * 384 + colOff + c];
    atomicAdd(p + 0, acc.x); atomicAdd(p + 1, acc.y);
    atomicAdd(p + 2, acc.z); atomicAdd(p + 3, acc.w);
    if (DO_CNT && cg == 0) atomicAdd(&cnt[curb], runc);
  }
}

// ---------------- JK: G = P(2048x384) @ W(384x128) + cnt*B ----------------
__global__ __launch_bounds__(256) void jk_gemm(
    const float* __restrict__ P, const float* __restrict__ cnt,
    const float* __restrict__ W, const float* __restrict__ B,
    float* __restrict__ G)
{
  __shared__ float pl[768];
  int tid = threadIdx.x, blk = blockIdx.x;
  for (int o = tid; o < 768; o += 256) pl[o] = P[(long)blk * 768 + o];
  __syncthreads();
  int rr = tid >> 7;       // 0..1
  int col = tid & 127;
  int row = blk * 2 + rr;
  float acc = cnt[row] * B[col];
#pragma unroll 8
  for (int k = 0; k < 384; ++k)
    acc += pl[rr * 384 + k] * W[k * 128 + col];
  G[(long)row * 128 + col] = acc;
}

// ---------------- batch-norm stats over 2048 rows ----------------
__global__ __launch_bounds__(256) void bn_stats(
    const float* __restrict__ ZC, const float* __restrict__ gma, const float* __restrict__ bta,
    float* __restrict__ scale, float* __restrict__ shift)
{
  int col = blockIdx.x;
  int tid = threadIdx.x;
  float s = 0.f, s2 = 0.f;
  for (int r = tid; r < NGRAPH; r += 256) {
    float v = ZC[(long)r * 128 + col];
    s += v; s2 += v * v;
  }
  for (int off = 32; off > 0; off >>= 1) {
    s += __shfl_down(s, off, 64);
    s2 += __shfl_down(s2, off, 64);
  }
  __shared__ float ls[4], ls2[4];
  int w = tid >> 6;
  if ((tid & 63) == 0) { ls[w] = s; ls2[w] = s2; }
  __syncthreads();
  if (tid == 0) {
    s = ls[0] + ls[1] + ls[2] + ls[3];
    s2 = ls2[0] + ls2[1] + ls2[2] + ls2[3];
    float mu = s * (1.f / NGRAPH);
    float var = s2 * (1.f / NGRAPH) - mu * mu;
    float rs = rsqrtf(var + 1e-5f);
    float sc = gma[col] * rs;
    scale[col] = sc;
    shift[col] = bta[col] - mu * sc;
  }
}

// ---------------- BN apply + relu + final [128x2] matmul ----------------
__global__ __launch_bounds__(256) void bn_final(
    const float* __restrict__ ZC, const float* __restrict__ scale, const float* __restrict__ shift,
    const float* __restrict__ W2, const float* __restrict__ B2, float* __restrict__ out)
{
  int g = blockIdx.x * 256 + threadIdx.x;
  if (g >= NGRAPH) return;
  float a0 = B2[0], a1 = B2[1];
#pragma unroll 4
  for (int h = 0; h < 128; ++h) {
    float zn = ZC[(long)g * 128 + h] * scale[h] + shift[h];
    zn = fmaxf(zn, 0.f);
    a0 += zn * W2[2 * h];
    a1 += zn * W2[2 * h + 1];
  }
  out[2 * g] = a0;
  out[2 * g + 1] = a1;
}

extern "C" void kernel_launch(void* const* d_in, const int* in_sizes, int n_in,
                              void* d_out, int out_size, void* d_ws, size_t ws_size,
                              hipStream_t stream)
{
  const float* x    = (const float*)d_in[0];
  const int*   ei   = (const int*)d_in[1];
  const int*   batch = (const int*)d_in[3];
  const float* g1w1 = (const float*)d_in[4];  const float* g1b1 = (const float*)d_in[5];
  const float* g1w2 = (const float*)d_in[6];  const float* g1b2 = (const float*)d_in[7];
  const float* g2w1 = (const float*)d_in[8];  const float* g2b1 = (const float*)d_in[9];
  const float* g2w2 = (const float*)d_in[10]; const float* g2b2 = (const float*)d_in[11];
  const float* g3w1 = (const float*)d_in[12]; const float* g3b1 = (const float*)d_in[13];
  const float* g3w2 = (const float*)d_in[14]; const float* g3b2 = (const float*)d_in[15];
  const float* jkw  = (const float*)d_in[16]; const float* jkb  = (const float*)d_in[17];
  const float* c1w  = (const float*)d_in[18]; const float* c1b  = (const float*)d_in[19];
  const float* bng  = (const float*)d_in[20]; const float* bnb  = (const float*)d_in[21];
  const float* c2w  = (const float*)d_in[22]; const float* c2b  = (const float*)d_in[23];

  const int N = in_sizes[3];
  const int E = in_sizes[1] / 2;
  const int* src = ei;
  const int* dst = ei + E;

  char* w = (char*)d_ws;
  auto alloc = [&](size_t bytes) {
    char* p = w;
    w += (bytes + 255) & ~(size_t)255;
    return p;
  };
  float* agg  = (float*)alloc((size_t)N * 128 * 4);
  float* y    = (float*)alloc((size_t)N * 128 * 4);
  float* hA   = (float*)alloc((size_t)N * 128 * 4);
  float* agg1 = (float*)alloc((size_t)N * 7 * 4);
  float* P    = (float*)alloc((size_t)NGRAPH * 384 * 4);
  float* cnt  = (float*)alloc((size_t)NGRAPH * 4);
  float* gbuf = (float*)alloc((size_t)NGRAPH * 128 * 4);
  float* zc   = (float*)alloc((size_t)NGRAPH * 128 * 4);
  float* scl  = (float*)alloc(128 * 4);
  float* shf  = (float*)alloc(128 * 4);

  hipMemsetAsync(agg1, 0, (size_t)N * 7 * 4, stream);
  hipMemsetAsync(P, 0, (size_t)NGRAPH * 384 * 4, stream);
  hipMemsetAsync(cnt, 0, (size_t)NGRAPH * 4, stream);

  const int gemmBlocks = (N + 63) / 64;
  const int poolBlocks = (((N + 15) / 16) * 32 + 255) / 256;
  const int scatBlocks = (int)(((long)E * 32 + 255) / 256);

  // ---- layer 1 ----
  scatter7<<<(int)(((long)E * 8 + 255) / 256), 256, 0, stream>>>(x, src, dst, agg1, E);
  gemm_in7<<<(N + 7) / 8, 256, 0, stream>>>(x, agg1, g1w1, g1b1, y, N);
  gemm_k128<true, false><<<gemmBlocks, 256, 0, stream>>>(y, nullptr, g1w2, g1b2, hA, N);
  pool128<true><<<poolBlocks, 256, 0, stream>>>(hA, batch, P, cnt, N, 0);

  // ---- layer 2 ----
  hipMemsetAsync(agg, 0, (size_t)N * 128 * 4, stream);
  scatter128<<<scatBlocks, 256, 0, stream>>>(hA, src, dst, agg, E);
  gemm_k128<true, true><<<gemmBlocks, 256, 0, stream>>>(hA, agg, g2w1, g2b1, y, N);
  gemm_k128<true, false><<<gemmBlocks, 256, 0, stream>>>(y, nullptr, g2w2, g2b2, hA, N);
  pool128<false><<<poolBlocks, 256, 0, stream>>>(hA, batch, P, cnt, N, 128);

  // ---- layer 3 ----
  hipMemsetAsync(agg, 0, (size_t)N * 128 * 4, stream);
  scatter128<<<scatBlocks, 256, 0, stream>>>(hA, src, dst, agg, E);
  gemm_k128<true, true><<<gemmBlocks, 256, 0, stream>>>(hA, agg, g3w1, g3b1, y, N);
  gemm_k128<true, false><<<gemmBlocks, 256, 0, stream>>>(y, nullptr, g3w2, g3b2, hA, N);
  pool128<false><<<poolBlocks, 256, 0, stream>>>(hA, batch, P, cnt, N, 256);

  // ---- head ----
  jk_gemm<<<NGRAPH / 2, 256, 0, stream>>>(P, cnt, jkw, jkb, gbuf);
  gemm_k128<false, false><<<(NGRAPH + 63) / 64, 256, 0, stream>>>(gbuf, nullptr, c1w, c1b, zc, NGRAPH);
  bn_stats<<<128, 256, 0, stream>>>(zc, bng, bnb, scl, shf);
  bn_final<<<(NGRAPH + 255) / 256, 256, 0, stream>>>(zc, scl, shf, c2w, c2b, (float*)d_out);
}

// Round 2
// 780.941 us; speedup vs baseline: 3.5819x; 3.5819x over previous
//
#include <hip/hip_runtime.h>

#define NGRAPH 2048

// ================= CSR build =================
__global__ __launch_bounds__(256) void hist_deg(
    const int* __restrict__ dst, int* __restrict__ deg, int E)
{
  int e = blockIdx.x * 256 + threadIdx.x;
  if (e < E) atomicAdd(&deg[dst[e]], 1);
}

// per-block exclusive scan of deg -> rowstart, block sums -> bsum
__global__ __launch_bounds__(256) void scan1(
    const int* __restrict__ deg, int* __restrict__ rowstart, int* __restrict__ bsum, int N)
{
  __shared__ int tmp[256];
  int i = blockIdx.x * 256 + threadIdx.x;
  int v = (i < N) ? deg[i] : 0;
  tmp[threadIdx.x] = v;
  __syncthreads();
#pragma unroll
  for (int off = 1; off < 256; off <<= 1) {
    int t = (threadIdx.x >= (unsigned)off) ? tmp[threadIdx.x - off] : 0;
    __syncthreads();
    tmp[threadIdx.x] += t;
    __syncthreads();
  }
  if (i < N) rowstart[i] = tmp[threadIdx.x] - v;  // exclusive within block
  if (threadIdx.x == 255) bsum[blockIdx.x] = tmp[255];
}

// single-block exclusive scan of block sums (nb <= 1024)
__global__ __launch_bounds__(1024) void scan2(
    int* __restrict__ bsum, int nb, int* __restrict__ rowstart, int N, int E)
{
  __shared__ int tmp[1024];
  int i = threadIdx.x;
  int v = (i < nb) ? bsum[i] : 0;
  tmp[i] = v;
  __syncthreads();
#pragma unroll
  for (int off = 1; off < 1024; off <<= 1) {
    int t = (i >= off) ? tmp[i - off] : 0;
    __syncthreads();
    tmp[i] += t;
    __syncthreads();
  }
  if (i < nb) bsum[i] = tmp[i] - v;  // exclusive
  if (i == 0) rowstart[N] = E;
}

__global__ __launch_bounds__(256) void scan3(
    int* __restrict__ rowstart, const int* __restrict__ bsum, int N)
{
  int i = blockIdx.x * 256 + threadIdx.x;
  if (i < N) rowstart[i] += bsum[blockIdx.x];
}

__global__ __launch_bounds__(256) void fill_eidx(
    const int* __restrict__ src, const int* __restrict__ dst,
    const int* __restrict__ rowstart, int* __restrict__ cursor,
    int* __restrict__ eidx, int E)
{
  int e = blockIdx.x * 256 + threadIdx.x;
  if (e >= E) return;
  int d = dst[e];
  int pos = rowstart[d] + atomicAdd(&cursor[d], 1);
  eidx[pos] = src[e];
}

// ================= gathers (replace scatters; include self term) =================
// z1[v] = x[v] + sum_{s in in(v)} x[s]   (7 features)
__global__ __launch_bounds__(256) void gather7(
    const float* __restrict__ x, const int* __restrict__ rowstart,
    const int* __restrict__ eidx, float* __restrict__ z1, int N)
{
  long t = (long)blockIdx.x * 256 + threadIdx.x;
  int v = (int)(t >> 3), j = (int)(t & 7);
  if (v >= N || j >= 7) return;
  float acc = x[(long)v * 7 + j];
  int e0 = rowstart[v], e1 = rowstart[v + 1];
  for (int e = e0; e < e1; ++e) {
    int s = eidx[e];
    acc += x[(long)s * 7 + j];
  }
  z1[(long)v * 7 + j] = acc;
}

// Z[v] = H[v] + sum_{s in in(v)} H[s]   (128 features, 32 lanes/node)
__global__ __launch_bounds__(256) void gather128(
    const float* __restrict__ H, const int* __restrict__ rowstart,
    const int* __restrict__ eidx, float* __restrict__ Z, int N)
{
  long t = (long)blockIdx.x * 256 + threadIdx.x;
  int v = (int)(t >> 5);
  if (v >= N) return;
  int c = (int)(t & 31) * 4;
  float4 acc = *(const float4*)&H[(long)v * 128 + c];
  int e0 = rowstart[v], e1 = rowstart[v + 1];
  for (int e = e0; e < e1; ++e) {
    int s = eidx[e];
    const float4 h = *(const float4*)&H[(long)s * 128 + c];
    acc.x += h.x; acc.y += h.y; acc.z += h.z; acc.w += h.w;
  }
  *(float4*)&Z[(long)v * 128 + c] = acc;
}

// ================= layer-1 first MLP: Y = relu(Z1 @ W(7x128) + B) =================
__global__ __launch_bounds__(256) void gemm_in7(
    const float* __restrict__ Z1,
    const float* __restrict__ W, const float* __restrict__ B,
    float* __restrict__ Y, int Nn)
{
  __shared__ float zl[8][8];
  int tid = threadIdx.x;
  int blk = blockIdx.x;
  if (tid < 56) {
    int rr = tid / 7, k = tid - rr * 7;
    int row = blk * 8 + rr;
    zl[rr][k] = (row < Nn) ? Z1[(long)row * 7 + k] : 0.f;
  }
  __syncthreads();
  int rr = tid >> 5;
  int c0 = (tid & 31) * 4;
  int row = blk * 8 + rr;
  float4 acc = *(const float4*)&B[c0];
#pragma unroll
  for (int k = 0; k < 7; ++k) {
    float z = zl[rr][k];
    float4 w = *(const float4*)&W[k * 128 + c0];
    acc.x += z * w.x; acc.y += z * w.y; acc.z += z * w.z; acc.w += z * w.w;
  }
  acc.x = fmaxf(acc.x, 0.f); acc.y = fmaxf(acc.y, 0.f);
  acc.z = fmaxf(acc.z, 0.f); acc.w = fmaxf(acc.w, 0.f);
  if (row < Nn) *(float4*)&Y[(long)row * 128 + c0] = acc;
}

// ================= generic K=128, 128-col GEMM: Out = act(Z @ W + B) =================
template <bool RELU>
__global__ __launch_bounds__(256) void gemm_k128(
    const float* __restrict__ Z,
    const float* __restrict__ W, const float* __restrict__ B,
    float* __restrict__ Out, int M)
{
  __shared__ float wl[128 * 128];
  int tid = threadIdx.x;
  {
    const float4* Ws = (const float4*)W;
    float4* Wd = (float4*)wl;
#pragma unroll
    for (int i = 0; i < 16; ++i) Wd[i * 256 + tid] = Ws[i * 256 + tid];
  }
  __syncthreads();

  int rg = tid >> 5;
  int c0 = (tid & 31) * 4;
  int rbase = blockIdx.x * 64 + rg * 8;

  int rcl[8];
#pragma unroll
  for (int i = 0; i < 8; ++i) {
    int r = rbase + i;
    rcl[i] = (r < M) ? r : (M - 1);
  }

  float acc[8][4];
#pragma unroll
  for (int i = 0; i < 8; ++i)
#pragma unroll
    for (int j = 0; j < 4; ++j) acc[i][j] = 0.f;

#pragma unroll 2
  for (int kc = 0; kc < 128; kc += 4) {
    float zv[8][4];
#pragma unroll
    for (int i = 0; i < 8; ++i) {
      float4 z = *(const float4*)&Z[(long)rcl[i] * 128 + kc];
      zv[i][0] = z.x; zv[i][1] = z.y; zv[i][2] = z.z; zv[i][3] = z.w;
    }
#pragma unroll
    for (int kk = 0; kk < 4; ++kk) {
      float4 w = *(const float4*)&wl[(kc + kk) * 128 + c0];
#pragma unroll
      for (int i = 0; i < 8; ++i) {
        float z = zv[i][kk];
        acc[i][0] += z * w.x; acc[i][1] += z * w.y;
        acc[i][2] += z * w.z; acc[i][3] += z * w.w;
      }
    }
  }

  float4 b = *(const float4*)&B[c0];
#pragma unroll
  for (int i = 0; i < 8; ++i) {
    int r = rbase + i;
    if (r < M) {
      float4 o;
      o.x = acc[i][0] + b.x; o.y = acc[i][1] + b.y;
      o.z = acc[i][2] + b.z; o.w = acc[i][3] + b.w;
      if (RELU) {
        o.x = fmaxf(o.x, 0.f); o.y = fmaxf(o.y, 0.f);
        o.z = fmaxf(o.z, 0.f); o.w = fmaxf(o.w, 0.f);
      }
      *(float4*)&Out[(long)r * 128 + c0] = o;
    }
  }
}

// ================= pooling =================
template <bool DO_CNT>
__global__ __launch_bounds__(256) void pool128(
    const float* __restrict__ H, const int* __restrict__ batch,
    float* __restrict__ P, float* __restrict__ cnt, int Nn, int colOff)
{
  long t = (long)blockIdx.x * 256 + threadIdx.x;
  int cg = (int)(t & 31);
  int chunk = (int)(t >> 5);
  int i0 = chunk * 16;
  if (i0 >= Nn) return;
  int c = cg * 4;
  float4 acc = {0.f, 0.f, 0.f, 0.f};
  int curb = -1;
  float runc = 0.f;
  for (int ii = 0; ii < 16; ++ii) {
    int i = i0 + ii;
    if (i >= Nn) break;
    int b = batch[i];
    if (b != curb) {
      if (curb >= 0) {
        float* p = &P[(long)curb * 384 + colOff + c];
        atomicAdd(p + 0, acc.x); atomicAdd(p + 1, acc.y);
        atomicAdd(p + 2, acc.z); atomicAdd(p + 3, acc.w);
        if (DO_CNT && cg == 0) atomicAdd(&cnt[curb], runc);
      }
      acc.x = acc.y = acc.z = acc.w = 0.f;
      runc = 0.f;
      curb = b;
    }
    const float4 v = *(const float4*)&H[(long)i * 128 + c];
    acc.x += v.x; acc.y += v.y; acc.z += v.z; acc.w += v.w;
    runc += 1.f;
  }
  if (curb >= 0) {
    float* p = &P[(long)curb * 384 + colOff + c];
    atomicAdd(p + 0, acc.x); atomicAdd(p + 1, acc.y);
    atomicAdd(p + 2, acc.z); atomicAdd(p + 3, acc.w);
    if (DO_CNT && cg == 0) atomicAdd(&cnt[curb], runc);
  }
}

// ================= JK: G = P(2048x384) @ W(384x128) + cnt*B =================
__global__ __launch_bounds__(256) void jk_gemm(
    const float* __restrict__ P, const float* __restrict__ cnt,
    const float* __restrict__ W, const float* __restrict__ B,
    float* __restrict__ G)
{
  __shared__ float pl[768];
  int tid = threadIdx.x, blk = blockIdx.x;
  for (int o = tid; o < 768; o += 256) pl[o] = P[(long)blk * 768 + o];
  __syncthreads();
  int rr = tid >> 7;
  int col = tid & 127;
  int row = blk * 2 + rr;
  float acc = cnt[row] * B[col];
#pragma unroll 8
  for (int k = 0; k < 384; ++k)
    acc += pl[rr * 384 + k] * W[k * 128 + col];
  G[(long)row * 128 + col] = acc;
}

// ================= batch-norm stats =================
__global__ __launch_bounds__(256) void bn_stats(
    const float* __restrict__ ZC, const float* __restrict__ gma, const float* __restrict__ bta,
    float* __restrict__ scale, float* __restrict__ shift)
{
  int col = blockIdx.x;
  int tid = threadIdx.x;
  float s = 0.f, s2 = 0.f;
  for (int r = tid; r < NGRAPH; r += 256) {
    float v = ZC[(long)r * 128 + col];
    s += v; s2 += v * v;
  }
  for (int off = 32; off > 0; off >>= 1) {
    s += __shfl_down(s, off, 64);
    s2 += __shfl_down(s2, off, 64);
  }
  __shared__ float ls[4], ls2[4];
  int w = tid >> 6;
  if ((tid & 63) == 0) { ls[w] = s; ls2[w] = s2; }
  __syncthreads();
  if (tid == 0) {
    s = ls[0] + ls[1] + ls[2] + ls[3];
    s2 = ls2[0] + ls2[1] + ls2[2] + ls2[3];
    float mu = s * (1.f / NGRAPH);
    float var = s2 * (1.f / NGRAPH) - mu * mu;
    float rs = rsqrtf(var + 1e-5f);
    float sc = gma[col] * rs;
    scale[col] = sc;
    shift[col] = bta[col] - mu * sc;
  }
}

// ================= BN apply + relu + final [128x2] matmul =================
__global__ __launch_bounds__(256) void bn_final(
    const float* __restrict__ ZC, const float* __restrict__ scale, const float* __restrict__ shift,
    const float* __restrict__ W2, const float* __restrict__ B2, float* __restrict__ out)
{
  int g = blockIdx.x * 256 + threadIdx.x;
  if (g >= NGRAPH) return;
  float a0 = B2[0], a1 = B2[1];
#pragma unroll 4
  for (int h = 0; h < 128; ++h) {
    float zn = ZC[(long)g * 128 + h] * scale[h] + shift[h];
    zn = fmaxf(zn, 0.f);
    a0 += zn * W2[2 * h];
    a1 += zn * W2[2 * h + 1];
  }
  out[2 * g] = a0;
  out[2 * g + 1] = a1;
}

extern "C" void kernel_launch(void* const* d_in, const int* in_sizes, int n_in,
                              void* d_out, int out_size, void* d_ws, size_t ws_size,
                              hipStream_t stream)
{
  const float* x    = (const float*)d_in[0];
  const int*   ei   = (const int*)d_in[1];
  const int*   batch = (const int*)d_in[3];
  const float* g1w1 = (const float*)d_in[4];  const float* g1b1 = (const float*)d_in[5];
  const float* g1w2 = (const float*)d_in[6];  const float* g1b2 = (const float*)d_in[7];
  const float* g2w1 = (const float*)d_in[8];  const float* g2b1 = (const float*)d_in[9];
  const float* g2w2 = (const float*)d_in[10]; const float* g2b2 = (const float*)d_in[11];
  const float* g3w1 = (const float*)d_in[12]; const float* g3b1 = (const float*)d_in[13];
  const float* g3w2 = (const float*)d_in[14]; const float* g3b2 = (const float*)d_in[15];
  const float* jkw  = (const float*)d_in[16]; const float* jkb  = (const float*)d_in[17];
  const float* c1w  = (const float*)d_in[18]; const float* c1b  = (const float*)d_in[19];
  const float* bng  = (const float*)d_in[20]; const float* bnb  = (const float*)d_in[21];
  const float* c2w  = (const float*)d_in[22]; const float* c2b  = (const float*)d_in[23];

  const int N = in_sizes[3];
  const int E = in_sizes[1] / 2;
  const int* src = ei;
  const int* dst = ei + E;

  char* w = (char*)d_ws;
  auto alloc = [&](size_t bytes) {
    char* p = w;
    w += (bytes + 255) & ~(size_t)255;
    return p;
  };
  float* y    = (float*)alloc((size_t)N * 128 * 4);
  float* hA   = (float*)alloc((size_t)N * 128 * 4);
  float* z    = (float*)alloc((size_t)N * 128 * 4);   // also holds z1 (N x 7) in layer 1
  float* P    = (float*)alloc((size_t)NGRAPH * 384 * 4);
  float* cnt  = (float*)alloc((size_t)NGRAPH * 4);
  float* gbuf = (float*)alloc((size_t)NGRAPH * 128 * 4);
  float* zc   = (float*)alloc((size_t)NGRAPH * 128 * 4);
  float* scl  = (float*)alloc(128 * 4);
  float* shf  = (float*)alloc(128 * 4);
  int* deg      = (int*)alloc((size_t)N * 4);
  int* cursor   = (int*)alloc((size_t)N * 4);
  int* rowstart = (int*)alloc((size_t)(N + 1) * 4);
  int* bsum     = (int*)alloc((size_t)1024 * 4);
  int* eidx     = (int*)alloc((size_t)E * 4);

  const int nb = (N + 255) / 256;           // scan blocks (391 for N=100k; must be <=1024)
  const int eb = (E + 255) / 256;

  // ---- CSR build (once; reused by all three layers) ----
  hipMemsetAsync(deg, 0, (size_t)N * 4, stream);
  hipMemsetAsync(cursor, 0, (size_t)N * 4, stream);
  hist_deg<<<eb, 256, 0, stream>>>(dst, deg, E);
  scan1<<<nb, 256, 0, stream>>>(deg, rowstart, bsum, N);
  scan2<<<1, 1024, 0, stream>>>(bsum, nb, rowstart, N, E);
  scan3<<<nb, 256, 0, stream>>>(rowstart, bsum, N);
  fill_eidx<<<eb, 256, 0, stream>>>(src, dst, rowstart, cursor, eidx, E);

  hipMemsetAsync(P, 0, (size_t)NGRAPH * 384 * 4, stream);
  hipMemsetAsync(cnt, 0, (size_t)NGRAPH * 4, stream);

  const int gemmBlocks = (N + 63) / 64;
  const int poolBlocks = (((N + 15) / 16) * 32 + 255) / 256;
  const int gathBlocks = (int)(((long)N * 32 + 255) / 256);

  float* z1 = z;  // alias: N x 7 fits in z

  // ---- layer 1 ----
  gather7<<<(int)(((long)N * 8 + 255) / 256), 256, 0, stream>>>(x, rowstart, eidx, z1, N);
  gemm_in7<<<(N + 7) / 8, 256, 0, stream>>>(z1, g1w1, g1b1, y, N);
  gemm_k128<true><<<gemmBlocks, 256, 0, stream>>>(y, g1w2, g1b2, hA, N);
  pool128<true><<<poolBlocks, 256, 0, stream>>>(hA, batch, P, cnt, N, 0);

  // ---- layer 2 ----
  gather128<<<gathBlocks, 256, 0, stream>>>(hA, rowstart, eidx, z, N);
  gemm_k128<true><<<gemmBlocks, 256, 0, stream>>>(z, g2w1, g2b1, y, N);
  gemm_k128<true><<<gemmBlocks, 256, 0, stream>>>(y, g2w2, g2b2, hA, N);
  pool128<false><<<poolBlocks, 256, 0, stream>>>(hA, batch, P, cnt, N, 128);

  // ---- layer 3 ----
  gather128<<<gathBlocks, 256, 0, stream>>>(hA, rowstart, eidx, z, N);
  gemm_k128<true><<<gemmBlocks, 256, 0, stream>>>(z, g3w1, g3b1, y, N);
  gemm_k128<true><<<gemmBlocks, 256, 0, stream>>>(y, g3w2, g3b2, hA, N);
  pool128<false><<<poolBlocks, 256, 0, stream>>>(hA, batch, P, cnt, N, 256);

  // ---- head ----
  jk_gemm<<<NGRAPH / 2, 256, 0, stream>>>(P, cnt, jkw, jkb, gbuf);
  gemm_k128<false><<<(NGRAPH + 63) / 64, 256, 0, stream>>>(gbuf, c1w, c1b, zc, NGRAPH);
  bn_stats<<<128, 256, 0, stream>>>(zc, bng, bnb, scl, shf);
  bn_final<<<(NGRAPH + 255) / 256, 256, 0, stream>>>(zc, scl, shf, c2w, c2b, (float*)d_out);
}

// Round 3
// 588.021 us; speedup vs baseline: 4.7571x; 1.3281x over previous
//
#include <hip/hip_runtime.h>

#define NGRAPH 2048

typedef __attribute__((ext_vector_type(8))) short bf16x8;
typedef __attribute__((ext_vector_type(4))) float f32x4;

__device__ inline unsigned short bf16_rne(float f) {
  union { float f; unsigned u; } c; c.f = f;
  unsigned u = c.u + 0x7fffu + ((c.u >> 16) & 1u);
  return (unsigned short)(u >> 16);
}
__device__ inline float bf16_to_f32(unsigned short h) {
  union { float f; unsigned u; } c; c.u = ((unsigned)h) << 16;
  return c.f;
}

// ================= CSR build =================
__global__ __launch_bounds__(256) void hist_deg(
    const int* __restrict__ dst, int* __restrict__ deg, int E)
{
  int e = blockIdx.x * 256 + threadIdx.x;
  if (e < E) atomicAdd(&deg[dst[e]], 1);
}

__global__ __launch_bounds__(256) void scan1(
    const int* __restrict__ deg, int* __restrict__ rowstart, int* __restrict__ bsum, int N)
{
  __shared__ int tmp[256];
  int i = blockIdx.x * 256 + threadIdx.x;
  int v = (i < N) ? deg[i] : 0;
  tmp[threadIdx.x] = v;
  __syncthreads();
#pragma unroll
  for (int off = 1; off < 256; off <<= 1) {
    int t = (threadIdx.x >= (unsigned)off) ? tmp[threadIdx.x - off] : 0;
    __syncthreads();
    tmp[threadIdx.x] += t;
    __syncthreads();
  }
  if (i < N) rowstart[i] = tmp[threadIdx.x] - v;
  if (threadIdx.x == 255) bsum[blockIdx.x] = tmp[255];
}

__global__ __launch_bounds__(1024) void scan2(
    int* __restrict__ bsum, int nb, int* __restrict__ rowstart, int N, int E)
{
  __shared__ int tmp[1024];
  int i = threadIdx.x;
  int v = (i < nb) ? bsum[i] : 0;
  tmp[i] = v;
  __syncthreads();
#pragma unroll
  for (int off = 1; off < 1024; off <<= 1) {
    int t = (i >= off) ? tmp[i - off] : 0;
    __syncthreads();
    tmp[i] += t;
    __syncthreads();
  }
  if (i < nb) bsum[i] = tmp[i] - v;
  if (i == 0) rowstart[N] = E;
}

__global__ __launch_bounds__(256) void scan3(
    int* __restrict__ rowstart, const int* __restrict__ bsum, int N)
{
  int i = blockIdx.x * 256 + threadIdx.x;
  if (i < N) rowstart[i] += bsum[blockIdx.x];
}

__global__ __launch_bounds__(256) void fill_eidx(
    const int* __restrict__ src, const int* __restrict__ dst,
    const int* __restrict__ rowstart, int* __restrict__ cursor,
    int* __restrict__ eidx, int E)
{
  int e = blockIdx.x * 256 + threadIdx.x;
  if (e >= E) return;
  int d = dst[e];
  int pos = rowstart[d] + atomicAdd(&cursor[d], 1);
  eidx[pos] = src[e];
}

// ================= gathers =================
__global__ __launch_bounds__(256) void gather7(
    const float* __restrict__ x, const int* __restrict__ rowstart,
    const int* __restrict__ eidx, float* __restrict__ z1, int N)
{
  long t = (long)blockIdx.x * 256 + threadIdx.x;
  int v = (int)(t >> 3), j = (int)(t & 7);
  if (v >= N || j >= 7) return;
  float acc = x[(long)v * 7 + j];
  int e0 = rowstart[v], e1 = rowstart[v + 1];
  for (int e = e0; e < e1; ++e) {
    int s = eidx[e];
    acc += x[(long)s * 7 + j];
  }
  z1[(long)v * 7 + j] = acc;
}

__global__ __launch_bounds__(256) void gather128(
    const float* __restrict__ H, const int* __restrict__ rowstart,
    const int* __restrict__ eidx, float* __restrict__ Z, int N)
{
  long t = (long)blockIdx.x * 256 + threadIdx.x;
  int v = (int)(t >> 5);
  if (v >= N) return;
  int c = (int)(t & 31) * 4;
  float4 acc = *(const float4*)&H[(long)v * 128 + c];
  int e0 = rowstart[v], e1 = rowstart[v + 1];
  for (int e = e0; e < e1; ++e) {
    int s = eidx[e];
    const float4 h = *(const float4*)&H[(long)s * 128 + c];
    acc.x += h.x; acc.y += h.y; acc.z += h.z; acc.w += h.w;
  }
  *(float4*)&Z[(long)v * 128 + c] = acc;
}

// ================= layer-1 first MLP (K=7, fp32 VALU) =================
__global__ __launch_bounds__(256) void gemm_in7(
    const float* __restrict__ Z1,
    const float* __restrict__ W, const float* __restrict__ B,
    float* __restrict__ Y, int Nn)
{
  __shared__ float zl[8][8];
  int tid = threadIdx.x;
  int blk = blockIdx.x;
  if (tid < 56) {
    int rr = tid / 7, k = tid - rr * 7;
    int row = blk * 8 + rr;
    zl[rr][k] = (row < Nn) ? Z1[(long)row * 7 + k] : 0.f;
  }
  __syncthreads();
  int rr = tid >> 5;
  int c0 = (tid & 31) * 4;
  int row = blk * 8 + rr;
  float4 acc = *(const float4*)&B[c0];
#pragma unroll
  for (int k = 0; k < 7; ++k) {
    float z = zl[rr][k];
    float4 w = *(const float4*)&W[k * 128 + c0];
    acc.x += z * w.x; acc.y += z * w.y; acc.z += z * w.z; acc.w += z * w.w;
  }
  acc.x = fmaxf(acc.x, 0.f); acc.y = fmaxf(acc.y, 0.f);
  acc.z = fmaxf(acc.z, 0.f); acc.w = fmaxf(acc.w, 0.f);
  if (row < Nn) *(float4*)&Y[(long)row * 128 + c0] = acc;
}

// ================= weight prep: W[k][n] f32 -> WT hi/lo bf16 [n][k] =================
__global__ __launch_bounds__(256) void wprep(
    const float* __restrict__ W, unsigned short* __restrict__ hi, unsigned short* __restrict__ lo)
{
  int i = blockIdx.x * 256 + threadIdx.x;    // 0..16383
  int k = i >> 7, n = i & 127;
  float w = W[i];
  unsigned short h = bf16_rne(w);
  float r = w - bf16_to_f32(h);
  hi[n * 128 + k] = h;
  lo[n * 128 + k] = bf16_rne(r);
}

// ================= MFMA GEMM: Out = relu(Z(Mx128) @ W(128x128) + B) =================
// split-precision bf16: acc = zh*wh + zh*wl + zl*wh (fp32 acc; ~fp32 accuracy)
// block = 256 thr = 4 waves; wave tile = 32 rows x 128 cols; block tile = 128 rows
__global__ __launch_bounds__(256) void gemm_mfma(
    const float* __restrict__ Z, const unsigned short* __restrict__ WThi,
    const unsigned short* __restrict__ WTlo, const float* __restrict__ B,
    float* __restrict__ Out, int M)
{
  __shared__ unsigned short wh[128 * 128];
  __shared__ unsigned short wl[128 * 128];
  int tid = threadIdx.x;
  {
    const uint4* sh = (const uint4*)WThi;
    const uint4* sl = (const uint4*)WTlo;
    uint4* dh = (uint4*)wh;
    uint4* dl = (uint4*)wl;
#pragma unroll
    for (int i = 0; i < 8; ++i) {
      dh[i * 256 + tid] = sh[i * 256 + tid];
      dl[i * 256 + tid] = sl[i * 256 + tid];
    }
  }
  __syncthreads();

  int lane = tid & 63;
  int wv = tid >> 6;
  int m16 = lane & 15;
  int quad = lane >> 4;
  int rbase = blockIdx.x * 128 + wv * 32;

  int row0 = rbase + m16;
  int row1 = rbase + 16 + m16;
  long rl0 = (row0 < M) ? row0 : (M - 1);
  long rl1 = (row1 < M) ? row1 : (M - 1);

  f32x4 acc[2][8];
#pragma unroll
  for (int rt = 0; rt < 2; ++rt)
#pragma unroll
    for (int t = 0; t < 8; ++t) acc[rt][t] = (f32x4){0.f, 0.f, 0.f, 0.f};

#pragma unroll
  for (int kc = 0; kc < 4; ++kc) {
    int k0 = kc * 32 + quad * 8;
    const float* zp0 = &Z[rl0 * 128 + k0];
    const float* zp1 = &Z[rl1 * 128 + k0];
    float4 a0 = *(const float4*)zp0;
    float4 a1 = *(const float4*)(zp0 + 4);
    float4 b0 = *(const float4*)zp1;
    float4 b1 = *(const float4*)(zp1 + 4);
    float v0[8] = {a0.x, a0.y, a0.z, a0.w, a1.x, a1.y, a1.z, a1.w};
    float v1[8] = {b0.x, b0.y, b0.z, b0.w, b1.x, b1.y, b1.z, b1.w};
    bf16x8 ah0, al0, ah1, al1;
#pragma unroll
    for (int j = 0; j < 8; ++j) {
      unsigned short h0 = bf16_rne(v0[j]);
      ah0[j] = (short)h0;
      al0[j] = (short)bf16_rne(v0[j] - bf16_to_f32(h0));
      unsigned short h1 = bf16_rne(v1[j]);
      ah1[j] = (short)h1;
      al1[j] = (short)bf16_rne(v1[j] - bf16_to_f32(h1));
    }
#pragma unroll
    for (int t = 0; t < 8; ++t) {
      int widx = (t * 16 + m16) * 128 + k0;
      bf16x8 bh = *(const bf16x8*)&wh[widx];
      bf16x8 bl = *(const bf16x8*)&wl[widx];
      acc[0][t] = __builtin_amdgcn_mfma_f32_16x16x32_bf16(ah0, bh, acc[0][t], 0, 0, 0);
      acc[0][t] = __builtin_amdgcn_mfma_f32_16x16x32_bf16(ah0, bl, acc[0][t], 0, 0, 0);
      acc[0][t] = __builtin_amdgcn_mfma_f32_16x16x32_bf16(al0, bh, acc[0][t], 0, 0, 0);
      acc[1][t] = __builtin_amdgcn_mfma_f32_16x16x32_bf16(ah1, bh, acc[1][t], 0, 0, 0);
      acc[1][t] = __builtin_amdgcn_mfma_f32_16x16x32_bf16(ah1, bl, acc[1][t], 0, 0, 0);
      acc[1][t] = __builtin_amdgcn_mfma_f32_16x16x32_bf16(al1, bh, acc[1][t], 0, 0, 0);
    }
  }

  float bias[8];
#pragma unroll
  for (int t = 0; t < 8; ++t) bias[t] = B[t * 16 + m16];

#pragma unroll
  for (int rt = 0; rt < 2; ++rt) {
    int r0 = rbase + rt * 16 + quad * 4;
#pragma unroll
    for (int i = 0; i < 4; ++i) {
      int r = r0 + i;
      if (r < M) {
#pragma unroll
        for (int t = 0; t < 8; ++t) {
          float o = acc[rt][t][i] + bias[t];
          Out[(long)r * 128 + t * 16 + m16] = fmaxf(o, 0.f);
        }
      }
    }
  }
}

// ================= fp32 GEMM kept for the small head (M=2048) =================
template <bool RELU>
__global__ __launch_bounds__(256) void gemm_k128(
    const float* __restrict__ Z,
    const float* __restrict__ W, const float* __restrict__ B,
    float* __restrict__ Out, int M)
{
  __shared__ float wlds[128 * 128];
  int tid = threadIdx.x;
  {
    const float4* Ws = (const float4*)W;
    float4* Wd = (float4*)wlds;
#pragma unroll
    for (int i = 0; i < 16; ++i) Wd[i * 256 + tid] = Ws[i * 256 + tid];
  }
  __syncthreads();

  int rg = tid >> 5;
  int c0 = (tid & 31) * 4;
  int rbase = blockIdx.x * 64 + rg * 8;

  int rcl[8];
#pragma unroll
  for (int i = 0; i < 8; ++i) {
    int r = rbase + i;
    rcl[i] = (r < M) ? r : (M - 1);
  }

  float acc[8][4];
#pragma unroll
  for (int i = 0; i < 8; ++i)
#pragma unroll
    for (int j = 0; j < 4; ++j) acc[i][j] = 0.f;

#pragma unroll 2
  for (int kc = 0; kc < 128; kc += 4) {
    float zv[8][4];
#pragma unroll
    for (int i = 0; i < 8; ++i) {
      float4 z = *(const float4*)&Z[(long)rcl[i] * 128 + kc];
      zv[i][0] = z.x; zv[i][1] = z.y; zv[i][2] = z.z; zv[i][3] = z.w;
    }
#pragma unroll
    for (int kk = 0; kk < 4; ++kk) {
      float4 w = *(const float4*)&wlds[(kc + kk) * 128 + c0];
#pragma unroll
      for (int i = 0; i < 8; ++i) {
        float z = zv[i][kk];
        acc[i][0] += z * w.x; acc[i][1] += z * w.y;
        acc[i][2] += z * w.z; acc[i][3] += z * w.w;
      }
    }
  }

  float4 b = *(const float4*)&B[c0];
#pragma unroll
  for (int i = 0; i < 8; ++i) {
    int r = rbase + i;
    if (r < M) {
      float4 o;
      o.x = acc[i][0] + b.x; o.y = acc[i][1] + b.y;
      o.z = acc[i][2] + b.z; o.w = acc[i][3] + b.w;
      if (RELU) {
        o.x = fmaxf(o.x, 0.f); o.y = fmaxf(o.y, 0.f);
        o.z = fmaxf(o.z, 0.f); o.w = fmaxf(o.w, 0.f);
      }
      *(float4*)&Out[(long)r * 128 + c0] = o;
    }
  }
}

// ================= pooling =================
template <bool DO_CNT>
__global__ __launch_bounds__(256) void pool128(
    const float* __restrict__ H, const int* __restrict__ batch,
    float* __restrict__ P, float* __restrict__ cnt, int Nn, int colOff)
{
  long t = (long)blockIdx.x * 256 + threadIdx.x;
  int cg = (int)(t & 31);
  int chunk = (int)(t >> 5);
  int i0 = chunk * 16;
  if (i0 >= Nn) return;
  int c = cg * 4;
  float4 acc = {0.f, 0.f, 0.f, 0.f};
  int curb = -1;
  float runc = 0.f;
  for (int ii = 0; ii < 16; ++ii) {
    int i = i0 + ii;
    if (i >= Nn) break;
    int b = batch[i];
    if (b != curb) {
      if (curb >= 0) {
        float* p = &P[(long)curb * 384 + colOff + c];
        atomicAdd(p + 0, acc.x); atomicAdd(p + 1, acc.y);
        atomicAdd(p + 2, acc.z); atomicAdd(p + 3, acc.w);
        if (DO_CNT && cg == 0) atomicAdd(&cnt[curb], runc);
      }
      acc.x = acc.y = acc.z = acc.w = 0.f;
      runc = 0.f;
      curb = b;
    }
    const float4 v = *(const float4*)&H[(long)i * 128 + c];
    acc.x += v.x; acc.y += v.y; acc.z += v.z; acc.w += v.w;
    runc += 1.f;
  }
  if (curb >= 0) {
    float* p = &P[(long)curb * 384 + colOff + c];
    atomicAdd(p + 0, acc.x); atomicAdd(p + 1, acc.y);
    atomicAdd(p + 2, acc.z); atomicAdd(p + 3, acc.w);
    if (DO_CNT && cg == 0) atomicAdd(&cnt[curb], runc);
  }
}

// ================= JK: G = P(2048x384) @ W(384x128) + cnt*B =================
__global__ __launch_bounds__(256) void jk_gemm(
    const float* __restrict__ P, const float* __restrict__ cnt,
    const float* __restrict__ W, const float* __restrict__ B,
    float* __restrict__ G)
{
  __shared__ float pl[768];
  int tid = threadIdx.x, blk = blockIdx.x;
  for (int o = tid; o < 768; o += 256) pl[o] = P[(long)blk * 768 + o];
  __syncthreads();
  int rr = tid >> 7;
  int col = tid & 127;
  int row = blk * 2 + rr;
  float acc = cnt[row] * B[col];
#pragma unroll 8
  for (int k = 0; k < 384; ++k)
    acc += pl[rr * 384 + k] * W[k * 128 + col];
  G[(long)row * 128 + col] = acc;
}

// ================= batch-norm stats =================
__global__ __launch_bounds__(256) void bn_stats(
    const float* __restrict__ ZC, const float* __restrict__ gma, const float* __restrict__ bta,
    float* __restrict__ scale, float* __restrict__ shift)
{
  int col = blockIdx.x;
  int tid = threadIdx.x;
  float s = 0.f, s2 = 0.f;
  for (int r = tid; r < NGRAPH; r += 256) {
    float v = ZC[(long)r * 128 + col];
    s += v; s2 += v * v;
  }
  for (int off = 32; off > 0; off >>= 1) {
    s += __shfl_down(s, off, 64);
    s2 += __shfl_down(s2, off, 64);
  }
  __shared__ float ls[4], ls2[4];
  int w = tid >> 6;
  if ((tid & 63) == 0) { ls[w] = s; ls2[w] = s2; }
  __syncthreads();
  if (tid == 0) {
    s = ls[0] + ls[1] + ls[2] + ls[3];
    s2 = ls2[0] + ls2[1] + ls2[2] + ls2[3];
    float mu = s * (1.f / NGRAPH);
    float var = s2 * (1.f / NGRAPH) - mu * mu;
    float rs = rsqrtf(var + 1e-5f);
    float sc = gma[col] * rs;
    scale[col] = sc;
    shift[col] = bta[col] - mu * sc;
  }
}

// ================= BN apply + relu + final [128x2] matmul =================
__global__ __launch_bounds__(256) void bn_final(
    const float* __restrict__ ZC, const float* __restrict__ scale, const float* __restrict__ shift,
    const float* __restrict__ W2, const float* __restrict__ B2, float* __restrict__ out)
{
  int g = blockIdx.x * 256 + threadIdx.x;
  if (g >= NGRAPH) return;
  float a0 = B2[0], a1 = B2[1];
#pragma unroll 4
  for (int h = 0; h < 128; ++h) {
    float zn = ZC[(long)g * 128 + h] * scale[h] + shift[h];
    zn = fmaxf(zn, 0.f);
    a0 += zn * W2[2 * h];
    a1 += zn * W2[2 * h + 1];
  }
  out[2 * g] = a0;
  out[2 * g + 1] = a1;
}

extern "C" void kernel_launch(void* const* d_in, const int* in_sizes, int n_in,
                              void* d_out, int out_size, void* d_ws, size_t ws_size,
                              hipStream_t stream)
{
  const float* x    = (const float*)d_in[0];
  const int*   ei   = (const int*)d_in[1];
  const int*   batch = (const int*)d_in[3];
  const float* g1w1 = (const float*)d_in[4];  const float* g1b1 = (const float*)d_in[5];
  const float* g1w2 = (const float*)d_in[6];  const float* g1b2 = (const float*)d_in[7];
  const float* g2w1 = (const float*)d_in[8];  const float* g2b1 = (const float*)d_in[9];
  const float* g2w2 = (const float*)d_in[10]; const float* g2b2 = (const float*)d_in[11];
  const float* g3w1 = (const float*)d_in[12]; const float* g3b1 = (const float*)d_in[13];
  const float* g3w2 = (const float*)d_in[14]; const float* g3b2 = (const float*)d_in[15];
  const float* jkw  = (const float*)d_in[16]; const float* jkb  = (const float*)d_in[17];
  const float* c1w  = (const float*)d_in[18]; const float* c1b  = (const float*)d_in[19];
  const float* bng  = (const float*)d_in[20]; const float* bnb  = (const float*)d_in[21];
  const float* c2w  = (const float*)d_in[22]; const float* c2b  = (const float*)d_in[23];

  const int N = in_sizes[3];
  const int E = in_sizes[1] / 2;
  const int* src = ei;
  const int* dst = ei + E;

  char* w = (char*)d_ws;
  auto alloc = [&](size_t bytes) {
    char* p = w;
    w += (bytes + 255) & ~(size_t)255;
    return p;
  };
  float* y    = (float*)alloc((size_t)N * 128 * 4);
  float* hA   = (float*)alloc((size_t)N * 128 * 4);
  float* z    = (float*)alloc((size_t)N * 128 * 4);   // z1 (N x 7) aliases here in layer 1
  float* P    = (float*)alloc((size_t)NGRAPH * 384 * 4);
  float* cnt  = (float*)alloc((size_t)NGRAPH * 4);
  float* gbuf = (float*)alloc((size_t)NGRAPH * 128 * 4);
  float* zc   = (float*)alloc((size_t)NGRAPH * 128 * 4);
  float* scl  = (float*)alloc(128 * 4);
  float* shf  = (float*)alloc(128 * 4);
  int* deg      = (int*)alloc((size_t)N * 4);
  int* cursor   = (int*)alloc((size_t)N * 4);
  int* rowstart = (int*)alloc((size_t)(N + 1) * 4);
  int* bsum     = (int*)alloc((size_t)1024 * 4);
  int* eidx     = (int*)alloc((size_t)E * 4);
  unsigned short* wtbuf = (unsigned short*)alloc((size_t)5 * 2 * 16384 * 2);

  unsigned short* WThi[5];
  unsigned short* WTlo[5];
  for (int m = 0; m < 5; ++m) {
    WThi[m] = wtbuf + (size_t)m * 2 * 16384;
    WTlo[m] = WThi[m] + 16384;
  }

  const int nb = (N + 255) / 256;
  const int eb = (E + 255) / 256;

  // ---- CSR build (reused by all three layers) ----
  hipMemsetAsync(deg, 0, (size_t)N * 4, stream);
  hipMemsetAsync(cursor, 0, (size_t)N * 4, stream);
  hist_deg<<<eb, 256, 0, stream>>>(dst, deg, E);
  scan1<<<nb, 256, 0, stream>>>(deg, rowstart, bsum, N);
  scan2<<<1, 1024, 0, stream>>>(bsum, nb, rowstart, N, E);
  scan3<<<nb, 256, 0, stream>>>(rowstart, bsum, N);
  fill_eidx<<<eb, 256, 0, stream>>>(src, dst, rowstart, cursor, eidx, E);

  // ---- weight prep for the 5 MFMA GEMMs ----
  wprep<<<64, 256, 0, stream>>>(g1w2, WThi[0], WTlo[0]);
  wprep<<<64, 256, 0, stream>>>(g2w1, WThi[1], WTlo[1]);
  wprep<<<64, 256, 0, stream>>>(g2w2, WThi[2], WTlo[2]);
  wprep<<<64, 256, 0, stream>>>(g3w1, WThi[3], WTlo[3]);
  wprep<<<64, 256, 0, stream>>>(g3w2, WThi[4], WTlo[4]);

  hipMemsetAsync(P, 0, (size_t)NGRAPH * 384 * 4, stream);
  hipMemsetAsync(cnt, 0, (size_t)NGRAPH * 4, stream);

  const int mfmaBlocks = (N + 127) / 128;
  const int poolBlocks = (((N + 15) / 16) * 32 + 255) / 256;
  const int gathBlocks = (int)(((long)N * 32 + 255) / 256);

  float* z1 = z;

  // ---- layer 1 ----
  gather7<<<(int)(((long)N * 8 + 255) / 256), 256, 0, stream>>>(x, rowstart, eidx, z1, N);
  gemm_in7<<<(N + 7) / 8, 256, 0, stream>>>(z1, g1w1, g1b1, y, N);
  gemm_mfma<<<mfmaBlocks, 256, 0, stream>>>(y, WThi[0], WTlo[0], g1b2, hA, N);
  pool128<true><<<poolBlocks, 256, 0, stream>>>(hA, batch, P, cnt, N, 0);

  // ---- layer 2 ----
  gather128<<<gathBlocks, 256, 0, stream>>>(hA, rowstart, eidx, z, N);
  gemm_mfma<<<mfmaBlocks, 256, 0, stream>>>(z, WThi[1], WTlo[1], g2b1, y, N);
  gemm_mfma<<<mfmaBlocks, 256, 0, stream>>>(y, WThi[2], WTlo[2], g2b2, hA, N);
  pool128<false><<<poolBlocks, 256, 0, stream>>>(hA, batch, P, cnt, N, 128);

  // ---- layer 3 ----
  gather128<<<gathBlocks, 256, 0, stream>>>(hA, rowstart, eidx, z, N);
  gemm_mfma<<<mfmaBlocks, 256, 0, stream>>>(z, WThi[3], WTlo[3], g3b1, y, N);
  gemm_mfma<<<mfmaBlocks, 256, 0, stream>>>(y, WThi[4], WTlo[4], g3b2, hA, N);
  pool128<false><<<poolBlocks, 256, 0, stream>>>(hA, batch, P, cnt, N, 256);

  // ---- head ----
  jk_gemm<<<NGRAPH / 2, 256, 0, stream>>>(P, cnt, jkw, jkb, gbuf);
  gemm_k128<false><<<(NGRAPH + 63) / 64, 256, 0, stream>>>(gbuf, c1w, c1b, zc, NGRAPH);
  bn_stats<<<128, 256, 0, stream>>>(zc, bng, bnb, scl, shf);
  bn_final<<<(NGRAPH + 255) / 256, 256, 0, stream>>>(zc, scl, shf, c2w, c2b, (float*)d_out);
}

// Round 4
// 542.368 us; speedup vs baseline: 5.1575x; 1.0842x over previous
//
#include <hip/hip_runtime.h>

#define NGRAPH 2048

typedef __attribute__((ext_vector_type(8))) short bf16x8;
typedef __attribute__((ext_vector_type(4))) float f32x4;

__device__ inline unsigned short bf16_rne(float f) {
  union { float f; unsigned u; } c; c.f = f;
  unsigned u = c.u + 0x7fffu + ((c.u >> 16) & 1u);
  return (unsigned short)(u >> 16);
}
__device__ inline float bf16_to_f32(unsigned short h) {
  union { float f; unsigned u; } c; c.u = ((unsigned)h) << 16;
  return c.f;
}

// ================= CSR build =================
__global__ __launch_bounds__(256) void hist_deg(
    const int* __restrict__ dst, int* __restrict__ deg, int E)
{
  int e = blockIdx.x * 256 + threadIdx.x;
  if (e < E) atomicAdd(&deg[dst[e]], 1);
}

__global__ __launch_bounds__(256) void scan1(
    const int* __restrict__ deg, int* __restrict__ rowstart, int* __restrict__ bsum, int N)
{
  __shared__ int tmp[256];
  int i = blockIdx.x * 256 + threadIdx.x;
  int v = (i < N) ? deg[i] : 0;
  tmp[threadIdx.x] = v;
  __syncthreads();
#pragma unroll
  for (int off = 1; off < 256; off <<= 1) {
    int t = (threadIdx.x >= (unsigned)off) ? tmp[threadIdx.x - off] : 0;
    __syncthreads();
    tmp[threadIdx.x] += t;
    __syncthreads();
  }
  if (i < N) rowstart[i] = tmp[threadIdx.x] - v;
  if (threadIdx.x == 255) bsum[blockIdx.x] = tmp[255];
}

__global__ __launch_bounds__(1024) void scan2(
    int* __restrict__ bsum, int nb, int* __restrict__ rowstart, int N, int E)
{
  __shared__ int tmp[1024];
  int i = threadIdx.x;
  int v = (i < nb) ? bsum[i] : 0;
  tmp[i] = v;
  __syncthreads();
#pragma unroll
  for (int off = 1; off < 1024; off <<= 1) {
    int t = (i >= off) ? tmp[i - off] : 0;
    __syncthreads();
    tmp[i] += t;
    __syncthreads();
  }
  if (i < nb) bsum[i] = tmp[i] - v;
  if (i == 0) rowstart[N] = E;
}

__global__ __launch_bounds__(256) void scan3(
    int* __restrict__ rowstart, const int* __restrict__ bsum, int N)
{
  int i = blockIdx.x * 256 + threadIdx.x;
  if (i < N) rowstart[i] += bsum[blockIdx.x];
}

__global__ __launch_bounds__(256) void fill_eidx(
    const int* __restrict__ src, const int* __restrict__ dst,
    const int* __restrict__ rowstart, int* __restrict__ cursor,
    int* __restrict__ eidx, int E)
{
  int e = blockIdx.x * 256 + threadIdx.x;
  if (e >= E) return;
  int d = dst[e];
  int pos = rowstart[d] + atomicAdd(&cursor[d], 1);
  eidx[pos] = src[e];
}

// ================= gathers =================
__global__ __launch_bounds__(256) void gather7(
    const float* __restrict__ x, const int* __restrict__ rowstart,
    const int* __restrict__ eidx, float* __restrict__ z1, int N)
{
  long t = (long)blockIdx.x * 256 + threadIdx.x;
  int v = (int)(t >> 3), j = (int)(t & 7);
  if (v >= N || j >= 7) return;
  float acc = x[(long)v * 7 + j];
  int e0 = rowstart[v], e1 = rowstart[v + 1];
  for (int e = e0; e < e1; ++e) {
    int s = eidx[e];
    acc += x[(long)s * 7 + j];
  }
  z1[(long)v * 7 + j] = acc;
}

// 32 lanes per node; 4-edge unroll -> 4 independent row loads in flight
__global__ __launch_bounds__(256) void gather128(
    const float* __restrict__ H, const int* __restrict__ rowstart,
    const int* __restrict__ eidx, float* __restrict__ Z, int N)
{
  long t = (long)blockIdx.x * 256 + threadIdx.x;
  int v = (int)(t >> 5);
  if (v >= N) return;
  int c = (int)(t & 31) * 4;
  const float* Hc = H + c;
  float4 a0 = *(const float4*)&Hc[(long)v * 128];
  float4 a1 = {0.f, 0.f, 0.f, 0.f};
  float4 a2 = {0.f, 0.f, 0.f, 0.f};
  float4 a3 = {0.f, 0.f, 0.f, 0.f};
  int e0 = rowstart[v], e1 = rowstart[v + 1];
  int e = e0;
  for (; e + 4 <= e1; e += 4) {
    int s0 = eidx[e], s1 = eidx[e + 1], s2 = eidx[e + 2], s3 = eidx[e + 3];
    float4 h0 = *(const float4*)&Hc[(long)s0 * 128];
    float4 h1 = *(const float4*)&Hc[(long)s1 * 128];
    float4 h2 = *(const float4*)&Hc[(long)s2 * 128];
    float4 h3 = *(const float4*)&Hc[(long)s3 * 128];
    a0.x += h0.x; a0.y += h0.y; a0.z += h0.z; a0.w += h0.w;
    a1.x += h1.x; a1.y += h1.y; a1.z += h1.z; a1.w += h1.w;
    a2.x += h2.x; a2.y += h2.y; a2.z += h2.z; a2.w += h2.w;
    a3.x += h3.x; a3.y += h3.y; a3.z += h3.z; a3.w += h3.w;
  }
  for (; e < e1; ++e) {
    int s = eidx[e];
    float4 h = *(const float4*)&Hc[(long)s * 128];
    a1.x += h.x; a1.y += h.y; a1.z += h.z; a1.w += h.w;
  }
  a0.x += a1.x + a2.x + a3.x;
  a0.y += a1.y + a2.y + a3.y;
  a0.z += a1.z + a2.z + a3.z;
  a0.w += a1.w + a2.w + a3.w;
  *(float4*)&Z[(long)v * 128 + c] = a0;
}

// ================= layer-1 first MLP (K=7, fp32 VALU) =================
__global__ __launch_bounds__(256) void gemm_in7(
    const float* __restrict__ Z1,
    const float* __restrict__ W, const float* __restrict__ B,
    float* __restrict__ Y, int Nn)
{
  __shared__ float zl[8][8];
  int tid = threadIdx.x;
  int blk = blockIdx.x;
  if (tid < 56) {
    int rr = tid / 7, k = tid - rr * 7;
    int row = blk * 8 + rr;
    zl[rr][k] = (row < Nn) ? Z1[(long)row * 7 + k] : 0.f;
  }
  __syncthreads();
  int rr = tid >> 5;
  int c0 = (tid & 31) * 4;
  int row = blk * 8 + rr;
  float4 acc = *(const float4*)&B[c0];
#pragma unroll
  for (int k = 0; k < 7; ++k) {
    float z = zl[rr][k];
    float4 w = *(const float4*)&W[k * 128 + c0];
    acc.x += z * w.x; acc.y += z * w.y; acc.z += z * w.z; acc.w += z * w.w;
  }
  acc.x = fmaxf(acc.x, 0.f); acc.y = fmaxf(acc.y, 0.f);
  acc.z = fmaxf(acc.z, 0.f); acc.w = fmaxf(acc.w, 0.f);
  if (row < Nn) *(float4*)&Y[(long)row * 128 + c0] = acc;
}

// ================= weight prep: W[k][n] f32 -> bf16 hi/lo in MFMA *fragment order* =================
// chunk c = (t*4 + kc)*64 + lane; element e in [0,8): n = t*16 + (lane&15), k = kc*32 + (lane>>4)*8 + e
// hi[c*8+e], lo[c*8+e]  (each plane 16384 ushorts = 32 KB)
__global__ __launch_bounds__(256) void wprep(
    const float* __restrict__ W, unsigned short* __restrict__ hi, unsigned short* __restrict__ lo)
{
  int j = blockIdx.x * 256 + threadIdx.x;    // 0..16383
  int c = j >> 3, e = j & 7;
  int t = c >> 8, kc = (c >> 6) & 3, lane = c & 63;
  int n = t * 16 + (lane & 15);
  int k = kc * 32 + (lane >> 4) * 8 + e;
  float w = W[k * 128 + n];
  unsigned short h = bf16_rne(w);
  float r = w - bf16_to_f32(h);
  hi[j] = h;
  lo[j] = bf16_rne(r);
}

// ================= MFMA GEMM: Out = relu(Z(Mx128) @ W(128x128) + B) =================
// split-precision bf16: acc = zh*wh + zh*wl + zl*wh (fp32 acc)
// 256 thr = 4 waves; wave tile = 64 rows x 128 cols; block tile = 256 rows
// W staged in LDS in fragment order -> conflict-free lane-contiguous ds_read_b128
__global__ __launch_bounds__(256, 2) void gemm_mfma(
    const float* __restrict__ Z, const unsigned short* __restrict__ Whi,
    const unsigned short* __restrict__ Wlo, const float* __restrict__ B,
    float* __restrict__ Out, int M)
{
  __shared__ unsigned short wh[16384];
  __shared__ unsigned short wl[16384];
  int tid = threadIdx.x;
  {
    const uint4* sh = (const uint4*)Whi;
    const uint4* sl = (const uint4*)Wlo;
    uint4* dh = (uint4*)wh;
    uint4* dl = (uint4*)wl;
#pragma unroll
    for (int i = 0; i < 8; ++i) {
      dh[i * 256 + tid] = sh[i * 256 + tid];
      dl[i * 256 + tid] = sl[i * 256 + tid];
    }
  }
  __syncthreads();

  int lane = tid & 63;
  int wv = tid >> 6;
  int m16 = lane & 15;
  int quad = lane >> 4;
  int rwave = blockIdx.x * 256 + wv * 64;

  long rl[4];
#pragma unroll
  for (int rt = 0; rt < 4; ++rt) {
    int r = rwave + rt * 16 + m16;
    rl[rt] = (r < M) ? r : (M - 1);
  }

  f32x4 acc[4][8];
#pragma unroll
  for (int rt = 0; rt < 4; ++rt)
#pragma unroll
    for (int t = 0; t < 8; ++t) acc[rt][t] = (f32x4){0.f, 0.f, 0.f, 0.f};

#pragma unroll
  for (int kc = 0; kc < 4; ++kc) {
    int k0 = kc * 32 + quad * 8;
    bf16x8 ah[4], al[4];
#pragma unroll
    for (int rt = 0; rt < 4; ++rt) {
      const float* zp = &Z[rl[rt] * 128 + k0];
      float4 z0 = *(const float4*)zp;
      float4 z1 = *(const float4*)(zp + 4);
      float v[8] = {z0.x, z0.y, z0.z, z0.w, z1.x, z1.y, z1.z, z1.w};
#pragma unroll
      for (int j = 0; j < 8; ++j) {
        unsigned short h = bf16_rne(v[j]);
        ah[rt][j] = (short)h;
        al[rt][j] = (short)bf16_rne(v[j] - bf16_to_f32(h));
      }
    }
#pragma unroll
    for (int t = 0; t < 8; ++t) {
      int cbase = ((t * 4 + kc) * 64 + lane) * 8;
      bf16x8 bh = *(const bf16x8*)&wh[cbase];
      bf16x8 bl = *(const bf16x8*)&wl[cbase];
#pragma unroll
      for (int rt = 0; rt < 4; ++rt) {
        acc[rt][t] = __builtin_amdgcn_mfma_f32_16x16x32_bf16(ah[rt], bh, acc[rt][t], 0, 0, 0);
        acc[rt][t] = __builtin_amdgcn_mfma_f32_16x16x32_bf16(ah[rt], bl, acc[rt][t], 0, 0, 0);
        acc[rt][t] = __builtin_amdgcn_mfma_f32_16x16x32_bf16(al[rt], bh, acc[rt][t], 0, 0, 0);
      }
    }
  }

  float bias[8];
#pragma unroll
  for (int t = 0; t < 8; ++t) bias[t] = B[t * 16 + m16];

#pragma unroll
  for (int rt = 0; rt < 4; ++rt) {
    int r0 = rwave + rt * 16 + quad * 4;
#pragma unroll
    for (int i = 0; i < 4; ++i) {
      int r = r0 + i;
      if (r < M) {
#pragma unroll
        for (int t = 0; t < 8; ++t) {
          float o = acc[rt][t][i] + bias[t];
          Out[(long)r * 128 + t * 16 + m16] = fmaxf(o, 0.f);
        }
      }
    }
  }
}

// ================= fp32 GEMM for the small head (M=2048) =================
template <bool RELU>
__global__ __launch_bounds__(256) void gemm_k128(
    const float* __restrict__ Z,
    const float* __restrict__ W, const float* __restrict__ B,
    float* __restrict__ Out, int M)
{
  __shared__ float wlds[128 * 128];
  int tid = threadIdx.x;
  {
    const float4* Ws = (const float4*)W;
    float4* Wd = (float4*)wlds;
#pragma unroll
    for (int i = 0; i < 16; ++i) Wd[i * 256 + tid] = Ws[i * 256 + tid];
  }
  __syncthreads();

  int rg = tid >> 5;
  int c0 = (tid & 31) * 4;
  int rbase = blockIdx.x * 64 + rg * 8;

  int rcl[8];
#pragma unroll
  for (int i = 0; i < 8; ++i) {
    int r = rbase + i;
    rcl[i] = (r < M) ? r : (M - 1);
  }

  float acc[8][4];
#pragma unroll
  for (int i = 0; i < 8; ++i)
#pragma unroll
    for (int j = 0; j < 4; ++j) acc[i][j] = 0.f;

#pragma unroll 2
  for (int kc = 0; kc < 128; kc += 4) {
    float zv[8][4];
#pragma unroll
    for (int i = 0; i < 8; ++i) {
      float4 z = *(const float4*)&Z[(long)rcl[i] * 128 + kc];
      zv[i][0] = z.x; zv[i][1] = z.y; zv[i][2] = z.z; zv[i][3] = z.w;
    }
#pragma unroll
    for (int kk = 0; kk < 4; ++kk) {
      float4 w = *(const float4*)&wlds[(kc + kk) * 128 + c0];
#pragma unroll
      for (int i = 0; i < 8; ++i) {
        float z = zv[i][kk];
        acc[i][0] += z * w.x; acc[i][1] += z * w.y;
        acc[i][2] += z * w.z; acc[i][3] += z * w.w;
      }
    }
  }

  float4 b = *(const float4*)&B[c0];
#pragma unroll
  for (int i = 0; i < 8; ++i) {
    int r = rbase + i;
    if (r < M) {
      float4 o;
      o.x = acc[i][0] + b.x; o.y = acc[i][1] + b.y;
      o.z = acc[i][2] + b.z; o.w = acc[i][3] + b.w;
      if (RELU) {
        o.x = fmaxf(o.x, 0.f); o.y = fmaxf(o.y, 0.f);
        o.z = fmaxf(o.z, 0.f); o.w = fmaxf(o.w, 0.f);
      }
      *(float4*)&Out[(long)r * 128 + c0] = o;
    }
  }
}

// ================= pooling =================
template <bool DO_CNT>
__global__ __launch_bounds__(256) void pool128(
    const float* __restrict__ H, const int* __restrict__ batch,
    float* __restrict__ P, float* __restrict__ cnt, int Nn, int colOff)
{
  long t = (long)blockIdx.x * 256 + threadIdx.x;
  int cg = (int)(t & 31);
  int chunk = (int)(t >> 5);
  int i0 = chunk * 16;
  if (i0 >= Nn) return;
  int c = cg * 4;
  float4 acc = {0.f, 0.f, 0.f, 0.f};
  int curb = -1;
  float runc = 0.f;
  for (int ii = 0; ii < 16; ++ii) {
    int i = i0 + ii;
    if (i >= Nn) break;
    int b = batch[i];
    if (b != curb) {
      if (curb >= 0) {
        float* p = &P[(long)curb * 384 + colOff + c];
        atomicAdd(p + 0, acc.x); atomicAdd(p + 1, acc.y);
        atomicAdd(p + 2, acc.z); atomicAdd(p + 3, acc.w);
        if (DO_CNT && cg == 0) atomicAdd(&cnt[curb], runc);
      }
      acc.x = acc.y = acc.z = acc.w = 0.f;
      runc = 0.f;
      curb = b;
    }
    const float4 v = *(const float4*)&H[(long)i * 128 + c];
    acc.x += v.x; acc.y += v.y; acc.z += v.z; acc.w += v.w;
    runc += 1.f;
  }
  if (curb >= 0) {
    float* p = &P[(long)curb * 384 + colOff + c];
    atomicAdd(p + 0, acc.x); atomicAdd(p + 1, acc.y);
    atomicAdd(p + 2, acc.z); atomicAdd(p + 3, acc.w);
    if (DO_CNT && cg == 0) atomicAdd(&cnt[curb], runc);
  }
}

// ================= JK: G = P(2048x384) @ W(384x128) + cnt*B =================
__global__ __launch_bounds__(256) void jk_gemm(
    const float* __restrict__ P, const float* __restrict__ cnt,
    const float* __restrict__ W, const float* __restrict__ B,
    float* __restrict__ G)
{
  __shared__ float pl[768];
  int tid = threadIdx.x, blk = blockIdx.x;
  for (int o = tid; o < 768; o += 256) pl[o] = P[(long)blk * 768 + o];
  __syncthreads();
  int rr = tid >> 7;
  int col = tid & 127;
  int row = blk * 2 + rr;
  float acc = cnt[row] * B[col];
#pragma unroll 8
  for (int k = 0; k < 384; ++k)
    acc += pl[rr * 384 + k] * W[k * 128 + col];
  G[(long)row * 128 + col] = acc;
}

// ================= batch-norm stats =================
__global__ __launch_bounds__(256) void bn_stats(
    const float* __restrict__ ZC, const float* __restrict__ gma, const float* __restrict__ bta,
    float* __restrict__ scale, float* __restrict__ shift)
{
  int col = blockIdx.x;
  int tid = threadIdx.x;
  float s = 0.f, s2 = 0.f;
  for (int r = tid; r < NGRAPH; r += 256) {
    float v = ZC[(long)r * 128 + col];
    s += v; s2 += v * v;
  }
  for (int off = 32; off > 0; off >>= 1) {
    s += __shfl_down(s, off, 64);
    s2 += __shfl_down(s2, off, 64);
  }
  __shared__ float ls[4], ls2[4];
  int w = tid >> 6;
  if ((tid & 63) == 0) { ls[w] = s; ls2[w] = s2; }
  __syncthreads();
  if (tid == 0) {
    s = ls[0] + ls[1] + ls[2] + ls[3];
    s2 = ls2[0] + ls2[1] + ls2[2] + ls2[3];
    float mu = s * (1.f / NGRAPH);
    float var = s2 * (1.f / NGRAPH) - mu * mu;
    float rs = rsqrtf(var + 1e-5f);
    float sc = gma[col] * rs;
    scale[col] = sc;
    shift[col] = bta[col] - mu * sc;
  }
}

// ================= BN apply + relu + final [128x2] matmul =================
__global__ __launch_bounds__(256) void bn_final(
    const float* __restrict__ ZC, const float* __restrict__ scale, const float* __restrict__ shift,
    const float* __restrict__ W2, const float* __restrict__ B2, float* __restrict__ out)
{
  int g = blockIdx.x * 256 + threadIdx.x;
  if (g >= NGRAPH) return;
  float a0 = B2[0], a1 = B2[1];
#pragma unroll 4
  for (int h = 0; h < 128; ++h) {
    float zn = ZC[(long)g * 128 + h] * scale[h] + shift[h];
    zn = fmaxf(zn, 0.f);
    a0 += zn * W2[2 * h];
    a1 += zn * W2[2 * h + 1];
  }
  out[2 * g] = a0;
  out[2 * g + 1] = a1;
}

extern "C" void kernel_launch(void* const* d_in, const int* in_sizes, int n_in,
                              void* d_out, int out_size, void* d_ws, size_t ws_size,
                              hipStream_t stream)
{
  const float* x    = (const float*)d_in[0];
  const int*   ei   = (const int*)d_in[1];
  const int*   batch = (const int*)d_in[3];
  const float* g1w1 = (const float*)d_in[4];  const float* g1b1 = (const float*)d_in[5];
  const float* g1w2 = (const float*)d_in[6];  const float* g1b2 = (const float*)d_in[7];
  const float* g2w1 = (const float*)d_in[8];  const float* g2b1 = (const float*)d_in[9];
  const float* g2w2 = (const float*)d_in[10]; const float* g2b2 = (const float*)d_in[11];
  const float* g3w1 = (const float*)d_in[12]; const float* g3b1 = (const float*)d_in[13];
  const float* g3w2 = (const float*)d_in[14]; const float* g3b2 = (const float*)d_in[15];
  const float* jkw  = (const float*)d_in[16]; const float* jkb  = (const float*)d_in[17];
  const float* c1w  = (const float*)d_in[18]; const float* c1b  = (const float*)d_in[19];
  const float* bng  = (const float*)d_in[20]; const float* bnb  = (const float*)d_in[21];
  const float* c2w  = (const float*)d_in[22]; const float* c2b  = (const float*)d_in[23];

  const int N = in_sizes[3];
  const int E = in_sizes[1] / 2;
  const int* src = ei;
  const int* dst = ei + E;

  char* w = (char*)d_ws;
  auto alloc = [&](size_t bytes) {
    char* p = w;
    w += (bytes + 255) & ~(size_t)255;
    return p;
  };
  float* y    = (float*)alloc((size_t)N * 128 * 4);
  float* hA   = (float*)alloc((size_t)N * 128 * 4);
  float* z    = (float*)alloc((size_t)N * 128 * 4);   // z1 (N x 7) aliases here in layer 1
  float* P    = (float*)alloc((size_t)NGRAPH * 384 * 4);
  float* cnt  = (float*)alloc((size_t)NGRAPH * 4);
  float* gbuf = (float*)alloc((size_t)NGRAPH * 128 * 4);
  float* zc   = (float*)alloc((size_t)NGRAPH * 128 * 4);
  float* scl  = (float*)alloc(128 * 4);
  float* shf  = (float*)alloc(128 * 4);
  int* deg      = (int*)alloc((size_t)N * 4);
  int* cursor   = (int*)alloc((size_t)N * 4);
  int* rowstart = (int*)alloc((size_t)(N + 1) * 4);
  int* bsum     = (int*)alloc((size_t)1024 * 4);
  int* eidx     = (int*)alloc((size_t)E * 4);
  unsigned short* wtbuf = (unsigned short*)alloc((size_t)5 * 2 * 16384 * 2);

  unsigned short* WThi[5];
  unsigned short* WTlo[5];
  for (int m = 0; m < 5; ++m) {
    WThi[m] = wtbuf + (size_t)m * 2 * 16384;
    WTlo[m] = WThi[m] + 16384;
  }

  const int nb = (N + 255) / 256;
  const int eb = (E + 255) / 256;

  // ---- CSR build (reused by all three layers) ----
  hipMemsetAsync(deg, 0, (size_t)N * 4, stream);
  hipMemsetAsync(cursor, 0, (size_t)N * 4, stream);
  hist_deg<<<eb, 256, 0, stream>>>(dst, deg, E);
  scan1<<<nb, 256, 0, stream>>>(deg, rowstart, bsum, N);
  scan2<<<1, 1024, 0, stream>>>(bsum, nb, rowstart, N, E);
  scan3<<<nb, 256, 0, stream>>>(rowstart, bsum, N);
  fill_eidx<<<eb, 256, 0, stream>>>(src, dst, rowstart, cursor, eidx, E);

  // ---- weight prep (fragment-ordered bf16 hi/lo) ----
  wprep<<<64, 256, 0, stream>>>(g1w2, WThi[0], WTlo[0]);
  wprep<<<64, 256, 0, stream>>>(g2w1, WThi[1], WTlo[1]);
  wprep<<<64, 256, 0, stream>>>(g2w2, WThi[2], WTlo[2]);
  wprep<<<64, 256, 0, stream>>>(g3w1, WThi[3], WTlo[3]);
  wprep<<<64, 256, 0, stream>>>(g3w2, WThi[4], WTlo[4]);

  hipMemsetAsync(P, 0, (size_t)NGRAPH * 384 * 4, stream);
  hipMemsetAsync(cnt, 0, (size_t)NGRAPH * 4, stream);

  const int mfmaBlocks = (N + 255) / 256;
  const int poolBlocks = (((N + 15) / 16) * 32 + 255) / 256;
  const int gathBlocks = (int)(((long)N * 32 + 255) / 256);

  float* z1 = z;

  // ---- layer 1 ----
  gather7<<<(int)(((long)N * 8 + 255) / 256), 256, 0, stream>>>(x, rowstart, eidx, z1, N);
  gemm_in7<<<(N + 7) / 8, 256, 0, stream>>>(z1, g1w1, g1b1, y, N);
  gemm_mfma<<<mfmaBlocks, 256, 0, stream>>>(y, WThi[0], WTlo[0], g1b2, hA, N);
  pool128<true><<<poolBlocks, 256, 0, stream>>>(hA, batch, P, cnt, N, 0);

  // ---- layer 2 ----
  gather128<<<gathBlocks, 256, 0, stream>>>(hA, rowstart, eidx, z, N);
  gemm_mfma<<<mfmaBlocks, 256, 0, stream>>>(z, WThi[1], WTlo[1], g2b1, y, N);
  gemm_mfma<<<mfmaBlocks, 256, 0, stream>>>(y, WThi[2], WTlo[2], g2b2, hA, N);
  pool128<false><<<poolBlocks, 256, 0, stream>>>(hA, batch, P, cnt, N, 128);

  // ---- layer 3 ----
  gather128<<<gathBlocks, 256, 0, stream>>>(hA, rowstart, eidx, z, N);
  gemm_mfma<<<mfmaBlocks, 256, 0, stream>>>(z, WThi[3], WTlo[3], g3b1, y, N);
  gemm_mfma<<<mfmaBlocks, 256, 0, stream>>>(y, WThi[4], WTlo[4], g3b2, hA, N);
  pool128<false><<<poolBlocks, 256, 0, stream>>>(hA, batch, P, cnt, N, 256);

  // ---- head ----
  jk_gemm<<<NGRAPH / 2, 256, 0, stream>>>(P, cnt, jkw, jkb, gbuf);
  gemm_k128<false><<<(NGRAPH + 63) / 64, 256, 0, stream>>>(gbuf, c1w, c1b, zc, NGRAPH);
  bn_stats<<<128, 256, 0, stream>>>(zc, bng, bnb, scl, shf);
  bn_final<<<(NGRAPH + 255) / 256, 256, 0, stream>>>(zc, scl, shf, c2w, c2b, (float*)d_out);
}